// Round 1
// baseline (449.180 us; speedup 1.0000x reference)
//
#include <hip/hip_runtime.h>
#include <math.h>

// Problem constants: token shape (b=16, c=16, n=25, h=16, w=128)
#define SB 819200   // batch stride = c*n*h*w
#define SC 51200    // c stride    = n*h*w
#define SN 2048     // n stride    = h*w
#define WDIM 128
#define NDIM 25
#define CH 256      // c*h
#define NW 3200     // n*w

// Swizzled index into a [BK][64] transposed LDS tile.
// Element (k, row) -> k*64 + ((row>>2) ^ (k>>2) & 15)*4 + (row&3)
// Keeps groups of 4 consecutive rows contiguous (float4-readable) while
// XOR-permuting the 16 row-groups per k so both the k-major stores and the
// row-major float4 reads are bank-conflict free.
__device__ __forceinline__ int swz(int k, int row) {
    return k * 64 + (((((row >> 2) ^ (k >> 2)) & 15)) << 2) + (row & 3);
}

// ---------------------------------------------------------------------------
// Kernel 1: inverse L2 norms of Q rows and K rows (both over the 3200 (n,w)
// elements of each (b,c,h) row).
// ---------------------------------------------------------------------------
__global__ __launch_bounds__(256) void norms_kernel(const float* __restrict__ q,
                                                    const float* __restrict__ k,
                                                    float* __restrict__ inv_nq,
                                                    float* __restrict__ inv_nk) {
    const int row = blockIdx.x;          // b*256 + t
    const int b = row >> 8;
    const int t = row & 255;
    const int c = t >> 4, h = t & 15;
    const size_t base = (size_t)b * SB + (size_t)c * SC + (size_t)h * WDIM;

    float sq = 0.f, sk = 0.f;
    for (int s = threadIdx.x; s < NW; s += 256) {
        const int n = s >> 7, w = s & 127;
        const size_t idx = base + (size_t)n * SN + w;
        const float a = q[idx];
        const float bb = k[idx];
        sq += a * a;
        sk += bb * bb;
    }
    __shared__ float redq[256];
    __shared__ float redk[256];
    redq[threadIdx.x] = sq;
    redk[threadIdx.x] = sk;
    __syncthreads();
    for (int off = 128; off > 0; off >>= 1) {
        if (threadIdx.x < off) {
            redq[threadIdx.x] += redq[threadIdx.x + off];
            redk[threadIdx.x] += redk[threadIdx.x + off];
        }
        __syncthreads();
    }
    if (threadIdx.x == 0) {
        inv_nq[row] = 1.0f / fmaxf(sqrtf(redq[0]), 1e-12f);
        inv_nk[row] = 1.0f / fmaxf(sqrtf(redk[0]), 1e-12f);
    }
}

// ---------------------------------------------------------------------------
// Kernel 2: S[b][t][r] = dot(Q_t, K_r) * inv_nq[t] * inv_nk[r]
// 64x64 tile per block, K=3200 in 50 chunks of 64, swizzled transposed LDS.
// grid (4, 4, 16) = 256 blocks, 256 threads.
// ---------------------------------------------------------------------------
__global__ __launch_bounds__(256) void gemm1_kernel(const float* __restrict__ q,
                                                    const float* __restrict__ k,
                                                    const float* __restrict__ inv_nq,
                                                    const float* __restrict__ inv_nk,
                                                    float* __restrict__ S) {
    __shared__ float As[64 * 64];
    __shared__ float Bs[64 * 64];

    const int b = blockIdx.z;
    const int tm = blockIdx.y;     // t-tile
    const int tn = blockIdx.x;     // r-tile
    const int tid = threadIdx.x;

    const int c4 = tid & 15;       // float4 column within 64-wide k-chunk
    const int lrow0 = tid >> 4;    // base row for loads (rows lrow0 + it*16)
    const int tx = tid & 15;       // r micro-tile group
    const int ty = tid >> 4;       // t micro-tile group

    float acc[4][4] = {};

    for (int ch = 0; ch < 50; ch++) {
        const int n = ch >> 1;
        const int half = ch & 1;
        const size_t colOff = (size_t)n * SN + half * 64 + c4 * 4;

        float4 av[4], bv[4];
#pragma unroll
        for (int it = 0; it < 4; it++) {
            const int row = lrow0 + it * 16;
            const int ra = tm * 64 + row;
            const int rb = tn * 64 + row;
            av[it] = *(const float4*)(q + (size_t)b * SB + (size_t)(ra >> 4) * SC +
                                      (size_t)(ra & 15) * WDIM + colOff);
            bv[it] = *(const float4*)(k + (size_t)b * SB + (size_t)(rb >> 4) * SC +
                                      (size_t)(rb & 15) * WDIM + colOff);
        }
        __syncthreads();   // previous iteration's compute reads done
#pragma unroll
        for (int it = 0; it < 4; it++) {
            const int row = lrow0 + it * 16;
            const int kb = c4 * 4;
            As[swz(kb + 0, row)] = av[it].x;
            As[swz(kb + 1, row)] = av[it].y;
            As[swz(kb + 2, row)] = av[it].z;
            As[swz(kb + 3, row)] = av[it].w;
            Bs[swz(kb + 0, row)] = bv[it].x;
            Bs[swz(kb + 1, row)] = bv[it].y;
            Bs[swz(kb + 2, row)] = bv[it].z;
            Bs[swz(kb + 3, row)] = bv[it].w;
        }
        __syncthreads();
#pragma unroll 8
        for (int kk = 0; kk < 64; kk++) {
            const float4 a4 = *(const float4*)&As[swz(kk, ty * 4)];
            const float4 b4 = *(const float4*)&Bs[swz(kk, tx * 4)];
            const float aa[4] = {a4.x, a4.y, a4.z, a4.w};
            const float bb[4] = {b4.x, b4.y, b4.z, b4.w};
#pragma unroll
            for (int i = 0; i < 4; i++)
#pragma unroll
                for (int j = 0; j < 4; j++)
                    acc[i][j] += aa[i] * bb[j];
        }
    }

    // epilogue: scale by inverse norms, store raw masked-later scores
    const int t0 = tm * 64 + ty * 4;
    const int r0 = tn * 64 + tx * 4;
    float snq[4], snk[4];
#pragma unroll
    for (int i = 0; i < 4; i++) snq[i] = inv_nq[b * CH + t0 + i];
#pragma unroll
    for (int j = 0; j < 4; j++) snk[j] = inv_nk[b * CH + r0 + j];
#pragma unroll
    for (int i = 0; i < 4; i++) {
        float4 o;
        o.x = acc[i][0] * snq[i] * snk[0];
        o.y = acc[i][1] * snq[i] * snk[1];
        o.z = acc[i][2] * snq[i] * snk[2];
        o.w = acc[i][3] * snq[i] * snk[3];
        *(float4*)(S + ((size_t)b * CH + t0 + i) * CH + r0) = o;
    }
}

// ---------------------------------------------------------------------------
// Kernel 3: causal mask + softmax over r for each (b, t) row, in place.
// grid (256, 16), 256 threads (one thread per r).
// ---------------------------------------------------------------------------
__global__ __launch_bounds__(256) void softmax_kernel(float* __restrict__ S) {
    const int t = blockIdx.x;
    const int b = blockIdx.y;
    float* row = S + ((size_t)b * CH + t) * CH;
    const int r = threadIdx.x;

    float val = (r <= t) ? row[r] : -1e15f;

    __shared__ float red[256];
    red[r] = val;
    __syncthreads();
    for (int off = 128; off > 0; off >>= 1) {
        if (r < off) red[r] = fmaxf(red[r], red[r + off]);
        __syncthreads();
    }
    const float m = red[0];
    __syncthreads();
    const float e = expf(val - m);   // masked entries -> exp(-huge) = 0
    red[r] = e;
    __syncthreads();
    for (int off = 128; off > 0; off >>= 1) {
        if (r < off) red[r] += red[r + off];
        __syncthreads();
    }
    row[r] = e / red[0];
}

// ---------------------------------------------------------------------------
// Kernel 4: O[t][(n,w)] = sum_r P[t][r] * V[r][(n,w)] + V_buffer, written to
// the original (b,c,n,h,w) layout. BM=64 t, BN=128 w (one n), K=256 r in 4
// chunks of 64. grid (25, 4, 16) = 1600 blocks, 256 threads.
// ---------------------------------------------------------------------------
__global__ __launch_bounds__(256) void gemm2_kernel(const float* __restrict__ P,
                                                    const float* __restrict__ v,
                                                    float* __restrict__ out) {
    __shared__ float Ps[64 * 64];     // [r][t] transposed swizzled
    __shared__ float Vs[64 * 132];    // [r][w] natural, padded

    const int b = blockIdx.z;
    const int tt = blockIdx.y;    // t-tile 0..3
    const int n = blockIdx.x;     // 0..24

    const int tid = threadIdx.x;
    const int tx = tid & 31;      // w-group: w = tx*4
    const int ty = tid >> 5;      // t-group: rows ty*8 .. +7

    float acc[8][4] = {};

    const int pc4 = tid & 15;
    const int prow0 = tid >> 4;
    const int vc4 = tid & 31;
    const int vrow0 = tid >> 5;

    for (int kc = 0; kc < 4; kc++) {
        float4 pv[4];
#pragma unroll
        for (int it = 0; it < 4; it++) {
            const int row = prow0 + it * 16;   // t-local
            pv[it] = *(const float4*)(P + ((size_t)b * CH + tt * 64 + row) * CH +
                                      kc * 64 + pc4 * 4);
        }
        float4 vv[8];
#pragma unroll
        for (int it = 0; it < 8; it++) {
            const int r = kc * 64 + vrow0 + it * 8;
            vv[it] = *(const float4*)(v + (size_t)b * SB + (size_t)(r >> 4) * SC +
                                      (size_t)n * SN + (size_t)(r & 15) * WDIM + vc4 * 4);
        }
        __syncthreads();
#pragma unroll
        for (int it = 0; it < 4; it++) {
            const int row = prow0 + it * 16;
            const int kb = pc4 * 4;
            Ps[swz(kb + 0, row)] = pv[it].x;
            Ps[swz(kb + 1, row)] = pv[it].y;
            Ps[swz(kb + 2, row)] = pv[it].z;
            Ps[swz(kb + 3, row)] = pv[it].w;
        }
#pragma unroll
        for (int it = 0; it < 8; it++) {
            *(float4*)&Vs[(vrow0 + it * 8) * 132 + vc4 * 4] = vv[it];
        }
        __syncthreads();
#pragma unroll 8
        for (int kk = 0; kk < 64; kk++) {
            const float4 a0 = *(const float4*)&Ps[swz(kk, ty * 8)];
            const float4 a1 = *(const float4*)&Ps[swz(kk, ty * 8 + 4)];
            const float4 b4 = *(const float4*)&Vs[kk * 132 + tx * 4];
            const float aa[8] = {a0.x, a0.y, a0.z, a0.w, a1.x, a1.y, a1.z, a1.w};
            const float bb[4] = {b4.x, b4.y, b4.z, b4.w};
#pragma unroll
            for (int i = 0; i < 8; i++)
#pragma unroll
                for (int j = 0; j < 4; j++)
                    acc[i][j] += aa[i] * bb[j];
        }
        __syncthreads();
    }

    // epilogue: add buffer (token_v) and store to (b,c,n,h,w) layout
#pragma unroll
    for (int i = 0; i < 8; i++) {
        const int t = tt * 64 + ty * 8 + i;
        const size_t addr = (size_t)b * SB + (size_t)(t >> 4) * SC + (size_t)n * SN +
                            (size_t)(t & 15) * WDIM + tx * 4;
        const float4 buf = *(const float4*)(v + addr);
        float4 o;
        o.x = acc[i][0] + buf.x;
        o.y = acc[i][1] + buf.y;
        o.z = acc[i][2] + buf.z;
        o.w = acc[i][3] + buf.w;
        *(float4*)(out + addr) = o;
    }
}

// ---------------------------------------------------------------------------
extern "C" void kernel_launch(void* const* d_in, const int* in_sizes, int n_in,
                              void* d_out, int out_size, void* d_ws, size_t ws_size,
                              hipStream_t stream) {
    const float* q = (const float*)d_in[0];
    const float* k = (const float*)d_in[1];
    const float* v = (const float*)d_in[2];
    float* out = (float*)d_out;

    float* ws = (float*)d_ws;
    float* inv_nq = ws;              // 4096 floats
    float* inv_nk = ws + 4096;       // 4096 floats
    float* S = ws + 8192;            // 16*256*256 = 1,048,576 floats (4 MB)

    norms_kernel<<<dim3(4096), dim3(256), 0, stream>>>(q, k, inv_nq, inv_nk);
    gemm1_kernel<<<dim3(4, 4, 16), dim3(256), 0, stream>>>(q, k, inv_nq, inv_nk, S);
    softmax_kernel<<<dim3(256, 16), dim3(256), 0, stream>>>(S);
    gemm2_kernel<<<dim3(25, 4, 16), dim3(256), 0, stream>>>(S, v, out);
}

// Round 2
// 243.037 us; speedup vs baseline: 1.8482x; 1.8482x over previous
//
#include <hip/hip_runtime.h>
#include <math.h>

// Problem constants: token shape (b=16, c=16, n=25, h=16, w=128)
#define SB 819200   // batch stride = c*n*h*w
#define SC 51200    // c stride    = n*h*w
#define SN 2048     // n stride    = h*w
#define CH 256      // c*h  (t dim)
#define NW 3200     // n*w  (k dim of gemm1, s dim of gemm2)
#define NPARTS 10
#define PARTLEN 320         // 3200 / 10, = 5 chunks of 64
#define SPART 1048576       // 16*256*256 floats per split-K partial

typedef __bf16 bf16x8 __attribute__((ext_vector_type(8)));
typedef float  f32x4  __attribute__((ext_vector_type(4)));

__device__ __forceinline__ bf16x8 cvt8(float4 a, float4 b) {
    bf16x8 r;
    r[0] = (__bf16)a.x; r[1] = (__bf16)a.y; r[2] = (__bf16)a.z; r[3] = (__bf16)a.w;
    r[4] = (__bf16)b.x; r[5] = (__bf16)b.y; r[6] = (__bf16)b.z; r[7] = (__bf16)b.w;
    return r;
}

// ---------------------------------------------------------------------------
// Kernel 1: inverse L2 norms of Q rows and K rows over the 3200-elem s-axis.
// grid 4096 (= b*256 + t), 256 threads, float4 loads.
// ---------------------------------------------------------------------------
__global__ __launch_bounds__(256) void norms_kernel(const float* __restrict__ q,
                                                    const float* __restrict__ k,
                                                    float* __restrict__ inv_nq,
                                                    float* __restrict__ inv_nk) {
    const int row = blockIdx.x;
    const int b = row >> 8;
    const int t = row & 255;
    const size_t base = (size_t)b * SB + (size_t)(t >> 4) * SC + (size_t)(t & 15) * 128;
    const float* qb = q + base;
    const float* kb = k + base;

    float sq = 0.f, sk = 0.f;
#pragma unroll
    for (int it = 0; it < 4; it++) {
        const int f4 = threadIdx.x + it * 256;   // 800 float4 per row
        if (f4 < 800) {
            const int s = f4 * 4;
            const size_t off = (size_t)(s >> 7) * SN + (s & 127);
            const float4 a = *(const float4*)(qb + off);
            const float4 c = *(const float4*)(kb + off);
            sq += a.x * a.x + a.y * a.y + a.z * a.z + a.w * a.w;
            sk += c.x * c.x + c.y * c.y + c.z * c.z + c.w * c.w;
        }
    }
    __shared__ float redq[256];
    __shared__ float redk[256];
    redq[threadIdx.x] = sq;
    redk[threadIdx.x] = sk;
    __syncthreads();
    for (int off = 128; off > 0; off >>= 1) {
        if (threadIdx.x < off) {
            redq[threadIdx.x] += redq[threadIdx.x + off];
            redk[threadIdx.x] += redk[threadIdx.x + off];
        }
        __syncthreads();
    }
    if (threadIdx.x == 0) {
        inv_nq[row] = 1.0f / fmaxf(sqrtf(redq[0]), 1e-12f);
        inv_nk[row] = 1.0f / fmaxf(sqrtf(redk[0]), 1e-12f);
    }
}

// ---------------------------------------------------------------------------
// Kernel 2: split-K bf16-MFMA GEMM for unnormalized scores.
// Spart[p][b][t][r] = sum_{k in part p} Q[t][k]*K[r][k]   (fp32 out)
// Block = 128x128 tile, 4 waves of 64x64 (4x4 C-tiles of 16x16x32).
// grid (3 causal 128-tiles, 10 parts, 16 b) = 480 blocks.
// Partials land in d_out used as scratch (10 * 4 MB <= 52 MB).
// ---------------------------------------------------------------------------
__global__ __launch_bounds__(256, 2) void gemm1_kernel(const float* __restrict__ q,
                                                       const float* __restrict__ k,
                                                       float* __restrict__ Sp) {
    __shared__ alignas(16) __bf16 As[128 * 72];
    __shared__ alignas(16) __bf16 Bs[128 * 72];

    const int tid = threadIdx.x;
    const int b = blockIdx.z;
    const int part = blockIdx.y;
    const int tile = blockIdx.x;           // 0:(0,0) 1:(1,0) 2:(1,1)
    const int tm = (tile + 1) >> 1;
    const int tn = tile >> 1;

    const int lane = tid & 63;
    const int wave = tid >> 6;
    const int wm = wave >> 1;              // wave m-half (64)
    const int wn = wave & 1;               // wave n-half (64)

    // staging coords: thread covers row = tid>>1, 32 floats at col (tid&1)*32
    const int srow = tid >> 1;
    const int scol = (tid & 1) * 32;
    const int ta = tm * 128 + srow;
    const int rb = tn * 128 + srow;
    const float* qrow = q + (size_t)b * SB + (size_t)(ta >> 4) * SC + (size_t)(ta & 15) * 128;
    const float* krow = k + (size_t)b * SB + (size_t)(rb >> 4) * SC + (size_t)(rb & 15) * 128;

    f32x4 acc[4][4] = {};
    bool live[4][4];
#pragma unroll
    for (int mi = 0; mi < 4; mi++)
#pragma unroll
        for (int ni = 0; ni < 4; ni++)
            live[mi][ni] = (tn * 128 + wn * 64 + ni * 16) <= (tm * 128 + wm * 64 + mi * 16);

    for (int ch = 0; ch < 5; ch++) {
        const int kg = part * PARTLEN + ch * 64;            // multiple of 64
        const size_t koff = (size_t)(kg >> 7) * SN + (kg & 127) + scol;

        float4 av[8], bv[8];
#pragma unroll
        for (int j = 0; j < 8; j++) {
            av[j] = *(const float4*)(qrow + koff + j * 4);
            bv[j] = *(const float4*)(krow + koff + j * 4);
        }
        __syncthreads();
#pragma unroll
        for (int j = 0; j < 4; j++) {
            *(bf16x8*)&As[srow * 72 + scol + j * 8] = cvt8(av[2 * j], av[2 * j + 1]);
            *(bf16x8*)&Bs[srow * 72 + scol + j * 8] = cvt8(bv[2 * j], bv[2 * j + 1]);
        }
        __syncthreads();
#pragma unroll
        for (int ks = 0; ks < 2; ks++) {
            const int ko = ks * 32 + (lane >> 4) * 8;
            bf16x8 af[4], bf[4];
#pragma unroll
            for (int mi = 0; mi < 4; mi++)
                af[mi] = *(const bf16x8*)&As[(wm * 64 + mi * 16 + (lane & 15)) * 72 + ko];
#pragma unroll
            for (int ni = 0; ni < 4; ni++)
                bf[ni] = *(const bf16x8*)&Bs[(wn * 64 + ni * 16 + (lane & 15)) * 72 + ko];
#pragma unroll
            for (int mi = 0; mi < 4; mi++)
#pragma unroll
                for (int ni = 0; ni < 4; ni++)
                    if (live[mi][ni])
                        acc[mi][ni] = __builtin_amdgcn_mfma_f32_16x16x32_bf16(
                            af[mi], bf[ni], acc[mi][ni], 0, 0, 0);
        }
    }

    float* o = Sp + (size_t)part * SPART + (size_t)b * 65536;
#pragma unroll
    for (int mi = 0; mi < 4; mi++)
#pragma unroll
        for (int ni = 0; ni < 4; ni++) {
            if (!live[mi][ni]) continue;
            const int r = tn * 128 + wn * 64 + ni * 16 + (lane & 15);
#pragma unroll
            for (int j = 0; j < 4; j++) {
                const int t = tm * 128 + wm * 64 + mi * 16 + (lane >> 4) * 4 + j;
                o[(size_t)t * 256 + r] = acc[mi][ni][j];
            }
        }
}

// ---------------------------------------------------------------------------
// Kernel 3: sum split-K partials, apply inverse norms, causal mask, softmax,
// write P as bf16. grid (256 t, 16 b), 256 threads (one per r).
// ---------------------------------------------------------------------------
__global__ __launch_bounds__(256) void softmax_kernel(const float* __restrict__ Sp,
                                                      const float* __restrict__ inv_nq,
                                                      const float* __restrict__ inv_nk,
                                                      __bf16* __restrict__ P) {
    const int t = blockIdx.x;
    const int b = blockIdx.y;
    const int r = threadIdx.x;
    const size_t idx = ((size_t)b * 256 + t) * 256 + r;

    float val = -1e30f;
    if (r <= t) {
        float s = 0.f;
#pragma unroll
        for (int p = 0; p < NPARTS; p++) s += Sp[(size_t)p * SPART + idx];
        val = s * inv_nq[b * 256 + t] * inv_nk[b * 256 + r];
    }
    __shared__ float red[256];
    red[r] = val;
    __syncthreads();
    for (int off = 128; off > 0; off >>= 1) {
        if (r < off) red[r] = fmaxf(red[r], red[r + off]);
        __syncthreads();
    }
    const float m = red[0];
    __syncthreads();
    const float e = (r <= t) ? expf(val - m) : 0.f;
    red[r] = e;
    __syncthreads();
    for (int off = 128; off > 0; off >>= 1) {
        if (r < off) red[r] += red[r + off];
        __syncthreads();
    }
    P[idx] = (__bf16)(e / red[0]);
}

// ---------------------------------------------------------------------------
// Kernel 4: O[t][s] = sum_r P[t][r]*V[r][s] + V[t][s], bf16 MFMA.
// Block = 128 t x 128 s (one n), K = 256 r in 4 chunks of 64.
// V is transposed into LDS [s][r] with an XOR swizzle keyed on s>>4 so the
// bf16 scatter stores are 2-way (free) and frag reads stay b128-aligned.
// grid (25 n, 2 t-tiles, 16 b) = 800 blocks.
// ---------------------------------------------------------------------------
__global__ __launch_bounds__(256, 2) void gemm2_kernel(const __bf16* __restrict__ P,
                                                       const float* __restrict__ v,
                                                       float* __restrict__ out) {
    __shared__ alignas(16) __bf16 Ps[128 * 72];   // [t][r] natural
    __shared__ alignas(16) __bf16 Vs[128 * 72];   // [s][r] transposed+swizzled

    const int tid = threadIdx.x;
    const int b = blockIdx.z;
    const int tt = blockIdx.y;
    const int n = blockIdx.x;

    const int lane = tid & 63;
    const int wave = tid >> 6;
    const int wm = wave >> 1;
    const int wn = wave & 1;

    // P staging: row = tid>>1, 32 bf16 at col (tid&1)*32
    const int prow = tid >> 1;
    const int pcol = (tid & 1) * 32;
    const __bf16* Prow = P + ((size_t)b * 256 + tt * 128 + prow) * 256;

    // V staging: w-group u = tid&7 (16 floats), r base = (tid>>3) (0..31)
    const int vu = tid & 7;
    const int vr = tid >> 3;
    const float* vbase = v + (size_t)b * SB + (size_t)n * SN;

    f32x4 acc[4][4] = {};

    for (int kc = 0; kc < 4; kc++) {
        bf16x8 p4[4];
#pragma unroll
        for (int j = 0; j < 4; j++)
            p4[j] = *(const bf16x8*)(Prow + kc * 64 + pcol + j * 8);

        float4 vv[2][4];
#pragma unroll
        for (int g = 0; g < 2; g++) {
            const int rg = kc * 64 + vr + g * 32;
            const float* vrow = vbase + (size_t)(rg >> 4) * SC + (size_t)(rg & 15) * 128;
#pragma unroll
            for (int jj = 0; jj < 4; jj++)
                vv[g][jj] = *(const float4*)(vrow + vu * 16 + jj * 4);
        }
        __syncthreads();
#pragma unroll
        for (int j = 0; j < 4; j++)
            *(bf16x8*)&Ps[prow * 72 + pcol + j * 8] = p4[j];
#pragma unroll
        for (int g = 0; g < 2; g++) {
            const int rl = vr + g * 32;              // r-local 0..63
            const int rsw = rl ^ (vu << 3);          // XOR swizzle keyed on s>>4 (=vu)
#pragma unroll
            for (int jj = 0; jj < 4; jj++) {
                const float* f = (const float*)&vv[g][jj];
#pragma unroll
                for (int e = 0; e < 4; e++) {
                    const int s = vu * 16 + jj * 4 + e;
                    Vs[s * 72 + rsw] = (__bf16)f[e];
                }
            }
        }
        __syncthreads();
#pragma unroll
        for (int ks = 0; ks < 2; ks++) {
            const int ko = ks * 32 + (lane >> 4) * 8;
            bf16x8 af[4], bf[4];
#pragma unroll
            for (int mi = 0; mi < 4; mi++)
                af[mi] = *(const bf16x8*)&Ps[(wm * 64 + mi * 16 + (lane & 15)) * 72 + ko];
#pragma unroll
            for (int ni = 0; ni < 4; ni++) {
                const int s0 = wn * 64 + ni * 16;
                const int sw = ((s0 >> 4) & 7) << 3;
                bf[ni] = *(const bf16x8*)&Vs[(s0 + (lane & 15)) * 72 + (ko ^ sw)];
            }
#pragma unroll
            for (int mi = 0; mi < 4; mi++)
#pragma unroll
                for (int ni = 0; ni < 4; ni++)
                    acc[mi][ni] = __builtin_amdgcn_mfma_f32_16x16x32_bf16(
                        af[mi], bf[ni], acc[mi][ni], 0, 0, 0);
        }
        __syncthreads();
    }

    // epilogue: add buffer (token_v at same address) and store strided
#pragma unroll
    for (int mi = 0; mi < 4; mi++)
#pragma unroll
        for (int j = 0; j < 4; j++) {
            const int t = tt * 128 + wm * 64 + mi * 16 + (lane >> 4) * 4 + j;
            const size_t base = (size_t)b * SB + (size_t)(t >> 4) * SC +
                                (size_t)n * SN + (size_t)(t & 15) * 128;
#pragma unroll
            for (int ni = 0; ni < 4; ni++) {
                const int w = wn * 64 + ni * 16 + (lane & 15);
                const size_t a = base + w;
                out[a] = acc[mi][ni][j] + v[a];
            }
        }
}

// ---------------------------------------------------------------------------
extern "C" void kernel_launch(void* const* d_in, const int* in_sizes, int n_in,
                              void* d_out, int out_size, void* d_ws, size_t ws_size,
                              hipStream_t stream) {
    const float* q = (const float*)d_in[0];
    const float* k = (const float*)d_in[1];
    const float* v = (const float*)d_in[2];
    float* out = (float*)d_out;

    float* ws = (float*)d_ws;
    float* inv_nq = ws;                        // 4096 floats
    float* inv_nk = ws + 4096;                 // 4096 floats
    __bf16* P = (__bf16*)(ws + 8192);          // 16*256*256 bf16 = 2 MB

    // d_out doubles as split-K scratch (10 * 4 MB = 42 MB <= 52 MB out),
    // fully overwritten by gemm2 afterwards.
    float* Spart = out;

    norms_kernel<<<dim3(4096), dim3(256), 0, stream>>>(q, k, inv_nq, inv_nk);
    gemm1_kernel<<<dim3(3, NPARTS, 16), dim3(256), 0, stream>>>(q, k, Spart);
    softmax_kernel<<<dim3(256, 16), dim3(256), 0, stream>>>(Spart, inv_nq, inv_nk, P);
    gemm2_kernel<<<dim3(25, 2, 16), dim3(256), 0, stream>>>(P, v, out);
}